// Round 7
// baseline (996.149 us; speedup 1.0000x reference)
//
#include <hip/hip_runtime.h>

#define BB 256
#define LL 1024
#define TT 128
#define NTH 512
#define CH 64    // backward chunk rows staged in LDS
#define TTP 129  // padded row stride for transposed trans (kills bank conflicts)

typedef unsigned long long ull;

// LDS-only barrier: does NOT drain vmcnt, so in-flight global loads/stores
// stay outstanding across it.
__device__ __forceinline__ void lds_barrier() {
    asm volatile("s_waitcnt lgkmcnt(0)\n\ts_barrier" ::);
}

// ===================== workspace variant =====================
// Forward: values-only Viterbi (no argmax bookkeeping), 2-phase reduce with
// wave-uniform broadcast state reads. Per step t stores the pre-emission max
// row m_t[j] to workspace. Backward: exact backpointer recovery via
// bit-exact score recompute + ballot first-match (== jnp.argmax first-index
// semantics, even under ties).
//
// __launch_bounds__(512, 2): 2 waves/EU min -> 256-VGPR budget. Without the
// second arg the compiler targets 8 waves/EU (~32 VGPRs) and REMATERIALIZES
// tc[32] from global memory inside the t-loop (r3-r6 showed VGPR_Count
// 32-52 with tc[32]/tc[64] declared — impossible unless spilled/reloaded).
// Occupancy is LDS-bound at 1 block/CU anyway, so the low cap bought nothing.
struct FwdSmem {
    float state[TT];          // current Viterbi state
    float pv[NTH];            // per-thread partial maxes
    unsigned char tags[LL];   // decoded tags staging
};

__global__ __launch_bounds__(NTH, 2)
void viterbi_ws_kernel(const float* __restrict__ x,
                       const int* __restrict__ lengths,
                       const float* __restrict__ trans,
                       int* __restrict__ out,
                       float* __restrict__ ws) {
    __shared__ FwdSmem sm;
    extern __shared__ float dyn[];            // tT[TTP*TT] | bm[CH*TT] | bx[CH*TT]
    float* tT = dyn;                          // tT[c*TTP + i] = trans[i*TT + c]
    float* bm = dyn + TTP * TT;               // staged m-history rows
    float* bx = bm + CH * TT;                 // staged x rows

    const int b   = blockIdx.x;
    const int tid = threadIdx.x;
    const int j   = tid & (TT - 1);   // tag column
    const int q   = tid >> 7;         // predecessor quarter

    int lenb = lengths[b];
    if (lenb < 1) lenb = 1;
    if (lenb > LL) lenb = LL;

    // Register-cache trans column slice: tc[ii] = trans[32q+ii][j].
    float tc[32];
    #pragma unroll
    for (int ii = 0; ii < 32; ++ii)
        tc[ii] = trans[(q * 32 + ii) * TT + j];

    // Transposed trans in LDS for the backward pass — padded stride TTP=129:
    // lanes write bank (j + r) % 32 -> 2-way (free). Re-read is L2-hot.
    #pragma unroll
    for (int ii = 0; ii < 32; ++ii) {
        int r = q * 32 + ii;
        tT[j * TTP + r] = trans[r * TT + j];
    }

    const float* xb  = x  + (size_t)b * LL * TT;
    float*       wsb = ws + (size_t)b * LL * TT;

    // row 0 of history := state_0 = x[0,:]
    if (tid < TT) { float v = xb[tid]; sm.state[tid] = v; wsb[tid] = v; }

    float xv = 0.0f, xn = 0.0f;
    if (tid < TT && lenb > 1) xv = xb[TT + j];
    lds_barrier();

    // ---------------- forward (values only) ----------------
    for (int t = 1; t < lenb; ++t) {
        if (tid < TT) {
            int tn = (t + 1 < lenb) ? (t + 1) : (lenb - 1);
            xn = xb[tn * TT + j];             // in flight across barriers
        }
        const float4* st4 = reinterpret_cast<const float4*>(sm.state + q * 32);
        float m0 = -3.4e38f, m1 = -3.4e38f, m2 = -3.4e38f, m3 = -3.4e38f;
        #pragma unroll
        for (int k = 0; k < 8; ++k) {
            float4 sv = st4[k];               // wave-uniform broadcast b128
            m0 = fmaxf(m0, sv.x + tc[4 * k + 0]);
            m1 = fmaxf(m1, sv.y + tc[4 * k + 1]);
            m2 = fmaxf(m2, sv.z + tc[4 * k + 2]);
            m3 = fmaxf(m3, sv.w + tc[4 * k + 3]);
        }
        sm.pv[tid] = fmaxf(fmaxf(m0, m1), fmaxf(m2, m3));
        lds_barrier();
        if (tid < TT) {
            float bv = fmaxf(fmaxf(sm.pv[j], sm.pv[j + 128]),
                             fmaxf(sm.pv[j + 256], sm.pv[j + 384]));
            wsb[t * TT + j] = bv;             // m_t row (pre-emission max)
            sm.state[j] = bv + xv;
            xv = xn;
        }
        lds_barrier();
    }

    // Drain our m-history stores and make them visible block-wide.
    __syncthreads();

    // ---- last_tag: exact first-index argmax over state (wave 0) ----
    int c = 0; float mv = 0.0f;
    const int l = tid;                        // lane id when tid < 64
    if (tid < 64) {
        float s0 = sm.state[l], s1 = sm.state[l + 64];
        float mm = fmaxf(s0, s1);
        #pragma unroll
        for (int off = 1; off < 64; off <<= 1)
            mm = fmaxf(mm, __shfl_xor(mm, off));
        ull blo = __ballot(s0 == mm);         // lo half: indices 0..63 (first)
        if (blo) c = __ffsll(blo) - 1;
        else     c = 64 + __ffsll(__ballot(s1 == mm)) - 1;
        if (lenb > 1) mv = wsb[(lenb - 1) * TT + c];   // m_{len-1}[c]
    }

    // ---- chunked backward walk (wave 0 walks; all threads stage) ----
    // Semantics (matches reference): tags[t] = c, THEN c = bp_t[c].
    int rhi = lenb - 2;                       // highest source row needed
    while (rhi >= 0) {
        int r0 = rhi - (CH - 1); if (r0 < 0) r0 = 0;
        int nrows = rhi - r0 + 1;
        const float4* wm4 = reinterpret_cast<const float4*>(wsb + r0 * TT);
        const float4* wx4 = reinterpret_cast<const float4*>(xb  + r0 * TT);
        float4* bm4 = reinterpret_cast<float4*>(bm);
        float4* bx4 = reinterpret_cast<float4*>(bx);
        int n4 = nrows * (TT / 4);
        for (int i4 = tid; i4 < n4; i4 += NTH) {
            bm4[i4] = wm4[i4];
            float4 v = wx4[i4];
            // row 0 holds state_0 directly: no emission re-add
            if (r0 == 0 && i4 < TT / 4) { v.x = 0.f; v.y = 0.f; v.z = 0.f; v.w = 0.f; }
            bx4[i4] = v;
        }
        lds_barrier();
        if (tid < 64) {
            for (int tt = r0 + nrows; tt >= r0 + 1; --tt) {
                int row = (tt - 1 - r0) * TT;
                // bit-exact recompute of forward scores:
                // state_{t-1}[i] = m + x (same operands/order as forward)
                float slo = (bm[row + l]      + bx[row + l])      + tT[c * TTP + l];
                float shi = (bm[row + 64 + l] + bx[row + 64 + l]) + tT[c * TTP + 64 + l];
                ull blo = __ballot(slo == mv);
                int nc;
                if (blo) nc = __ffsll(blo) - 1;              // first i in 0..63
                else     nc = 64 + __ffsll(__ballot(shi == mv)) - 1;
                if (l == 0) sm.tags[tt] = (unsigned char)c;  // CURRENT tag at tt
                c = nc;                                      // tag at tt-1
                mv = bm[row + c];             // m_{tt-1}[c] for next step
            }
        }
        lds_barrier();                        // protect bm/bx before reload
        rhi = r0 - 1;
    }
    if (tid == 0) sm.tags[0] = (unsigned char)c;
    lds_barrier();

    int* outb = out + (size_t)b * LL;
    for (int tt = tid; tt < LL; tt += NTH)
        outb[tt] = (tt < lenb) ? (int)sm.tags[tt] : 0;
}

// ===================== fallback (no workspace): round-0 kernel =====================
struct SmallSmem {
    float state[TT];
    float pv[NTH];
    int   pi[NTH];
    unsigned char tags[LL];
};

__global__ __launch_bounds__(NTH, 2)
void viterbi_kernel(const float* __restrict__ x,
                    const int* __restrict__ lengths,
                    const float* __restrict__ trans,
                    int* __restrict__ out) {
    __shared__ SmallSmem sm;
    extern __shared__ unsigned char bp[];   // LL*TT bytes

    const int b   = blockIdx.x;
    const int tid = threadIdx.x;
    const int j   = tid & (TT - 1);
    const int q   = tid >> 7;

    int lenb = lengths[b];
    if (lenb < 1) lenb = 1;
    if (lenb > LL) lenb = LL;

    float tc[32];
    #pragma unroll
    for (int ii = 0; ii < 32; ++ii)
        tc[ii] = trans[(q * 32 + ii) * TT + j];

    const float* xb = x + (size_t)b * LL * TT;
    if (tid < TT) sm.state[tid] = xb[tid];

    float xv_cur = 0.0f, xv_next = 0.0f;
    if (tid < TT && lenb > 1) xv_cur = xb[TT + j];
    lds_barrier();

    for (int t = 1; t < lenb; ++t) {
        if (tid < TT) {
            int tn = (t + 1 < lenb) ? (t + 1) : (lenb - 1);
            xv_next = xb[tn * TT + j];
        }
        float best0 = -3.4e38f, best1 = -3.4e38f, best2 = -3.4e38f, best3 = -3.4e38f;
        int   bi0 = 0, bi1 = 1, bi2 = 2, bi3 = 3;
        const float4* st4 = reinterpret_cast<const float4*>(sm.state + q * 32);
        #pragma unroll
        for (int k = 0; k < 8; ++k) {
            float4 sv = st4[k];
            float s0 = sv.x + tc[4 * k + 0];
            float s1 = sv.y + tc[4 * k + 1];
            float s2 = sv.z + tc[4 * k + 2];
            float s3 = sv.w + tc[4 * k + 3];
            if (s0 > best0) { best0 = s0; bi0 = 4 * k + 0; }
            if (s1 > best1) { best1 = s1; bi1 = 4 * k + 1; }
            if (s2 > best2) { best2 = s2; bi2 = 4 * k + 2; }
            if (s3 > best3) { best3 = s3; bi3 = 4 * k + 3; }
        }
        float bb = best0; int bi = bi0;
        if (best1 > bb || (best1 == bb && bi1 < bi)) { bb = best1; bi = bi1; }
        if (best2 > bb || (best2 == bb && bi2 < bi)) { bb = best2; bi = bi2; }
        if (best3 > bb || (best3 == bb && bi3 < bi)) { bb = best3; bi = bi3; }
        sm.pv[tid] = bb;
        sm.pi[tid] = bi + q * 32;
        lds_barrier();

        if (tid < TT) {
            float bv = sm.pv[j];       int ix = sm.pi[j];
            float v1 = sm.pv[j + 128]; int i1 = sm.pi[j + 128];
            float v2 = sm.pv[j + 256]; int i2 = sm.pi[j + 256];
            float v3 = sm.pv[j + 384]; int i3 = sm.pi[j + 384];
            if (v1 > bv) { bv = v1; ix = i1; }
            if (v2 > bv) { bv = v2; ix = i2; }
            if (v3 > bv) { bv = v3; ix = i3; }
            sm.state[j] = bv + xv_cur;
            bp[t * TT + j] = (unsigned char)ix;
            xv_cur = xv_next;
        }
        lds_barrier();
    }

    if (tid == 0) {
        float bv = sm.state[0]; int ix = 0;
        for (int i = 1; i < TT; ++i) {
            float v = sm.state[i];
            if (v > bv) { bv = v; ix = i; }
        }
        int carry = ix;
        for (int t = lenb - 1; t >= 1; --t) {
            sm.tags[t] = (unsigned char)carry;
            carry = bp[t * TT + carry];
        }
        sm.tags[0] = (unsigned char)carry;
    }
    lds_barrier();

    int* outb = out + (size_t)b * LL;
    for (int t = tid; t < LL; t += NTH)
        outb[t] = (t < lenb) ? (int)sm.tags[t] : 0;
}

extern "C" void kernel_launch(void* const* d_in, const int* in_sizes, int n_in,
                              void* d_out, int out_size, void* d_ws, size_t ws_size,
                              hipStream_t stream) {
    const float* x       = (const float*)d_in[0];
    const int*   lengths = (const int*)d_in[1];
    // d_in[2] = tags (unused by decode)
    const float* trans   = (const float*)d_in[3];
    int*         out     = (int*)d_out;

    const size_t ws_needed = (size_t)BB * LL * TT * sizeof(float);  // 134 MB

    if (d_ws != nullptr && ws_size >= ws_needed) {
        // tT (padded, 64.5 KB) + bm/bx staging (64 KB) dynamic; ~3.6 KB static
        const int dyn = (TTP * TT + 2 * CH * TT) * (int)sizeof(float);  // 131584
        hipFuncSetAttribute((const void*)&viterbi_ws_kernel,
                            hipFuncAttributeMaxDynamicSharedMemorySize, dyn);
        viterbi_ws_kernel<<<BB, NTH, dyn, stream>>>(x, lengths, trans, out,
                                                    (float*)d_ws);
    } else {
        const int dyn = LL * TT;  // 131072 bytes of backpointers
        hipFuncSetAttribute((const void*)&viterbi_kernel,
                            hipFuncAttributeMaxDynamicSharedMemorySize, dyn);
        viterbi_kernel<<<BB, NTH, dyn, stream>>>(x, lengths, trans, out);
    }
}

// Round 8
// 764.317 us; speedup vs baseline: 1.3033x; 1.3033x over previous
//
#include <hip/hip_runtime.h>

#define BB 256
#define LL 1024
#define TT 128
#define NTH 512
#define CH 64    // backward chunk rows staged in LDS
#define TTP 129  // padded row stride for transposed trans (kills bank conflicts)

typedef unsigned long long ull;

// LDS-only barrier: does NOT drain vmcnt, so in-flight global loads/stores
// stay outstanding across it.
__device__ __forceinline__ void lds_barrier() {
    asm volatile("s_waitcnt lgkmcnt(0)\n\ts_barrier" ::);
}

// ===================== workspace variant =====================
// Forward: values-only Viterbi (no argmax bookkeeping), 2-phase reduce with
// wave-uniform broadcast state reads. Per step t stores the pre-emission max
// row m_t[j] to workspace. Backward: exact backpointer recovery via
// bit-exact score recompute + ballot first-match (== jnp.argmax first-index
// semantics, even under ties).
//
// tc[] PIN: rocprof showed VGPR_Count=32..52 across r0-r7 with a declared
// 32-64 float register cache — impossible if resident. With dynamic LDS the
// compiler can't see we're 1 block/CU, so it chases a high-occupancy VGPR
// tier and SINKS the tc loads into the t-loop: 32 stride-512B (non-
// vectorizable) global_load_dword per thread PER STEP ≈ the entire ~1200
// unexplained cycles/step. asm volatile "+v" makes each tc value's only
// reaching definition an opaque register — remat from memory is impossible.
struct FwdSmem {
    float state[TT];          // current Viterbi state
    float pv[NTH];            // per-thread partial maxes
    unsigned char tags[LL];   // decoded tags staging
};

__global__ __launch_bounds__(NTH)
void viterbi_ws_kernel(const float* __restrict__ x,
                       const int* __restrict__ lengths,
                       const float* __restrict__ trans,
                       int* __restrict__ out,
                       float* __restrict__ ws) {
    __shared__ FwdSmem sm;
    extern __shared__ float dyn[];            // tT[TTP*TT] | bm[CH*TT] | bx[CH*TT]
    float* tT = dyn;                          // tT[c*TTP + i] = trans[i*TT + c]
    float* bm = dyn + TTP * TT;               // staged m-history rows
    float* bx = bm + CH * TT;                 // staged x rows

    const int b   = blockIdx.x;
    const int tid = threadIdx.x;
    const int j   = tid & (TT - 1);   // tag column
    const int q   = tid >> 7;         // predecessor quarter

    int lenb = lengths[b];
    if (lenb < 1) lenb = 1;
    if (lenb > LL) lenb = LL;

    // Register-cache trans column slice: tc[ii] = trans[32q+ii][j].
    float tc[32];
    #pragma unroll
    for (int ii = 0; ii < 32; ++ii)
        tc[ii] = trans[(q * 32 + ii) * TT + j];
    // Pin in VGPRs (see header comment) — forbids in-loop remat.
    #pragma unroll
    for (int ii = 0; ii < 32; ++ii)
        asm volatile("" : "+v"(tc[ii]));

    // Transposed trans in LDS for the backward pass — padded stride TTP=129:
    // lanes write bank (j + r) % 32 -> 2-way (free). Re-read is L2-hot.
    #pragma unroll
    for (int ii = 0; ii < 32; ++ii) {
        int r = q * 32 + ii;
        tT[j * TTP + r] = trans[r * TT + j];
    }

    const float* xb  = x  + (size_t)b * LL * TT;
    float*       wsb = ws + (size_t)b * LL * TT;

    // row 0 of history := state_0 = x[0,:]
    if (tid < TT) { float v = xb[tid]; sm.state[tid] = v; wsb[tid] = v; }

    float xv = 0.0f, xn = 0.0f;
    if (tid < TT && lenb > 1) xv = xb[TT + j];
    lds_barrier();

    // ---------------- forward (values only) ----------------
    for (int t = 1; t < lenb; ++t) {
        if (tid < TT) {
            int tn = (t + 1 < lenb) ? (t + 1) : (lenb - 1);
            xn = xb[tn * TT + j];             // in flight across barriers
        }
        const float4* st4 = reinterpret_cast<const float4*>(sm.state + q * 32);
        float m0 = -3.4e38f, m1 = -3.4e38f, m2 = -3.4e38f, m3 = -3.4e38f;
        #pragma unroll
        for (int k = 0; k < 8; ++k) {
            float4 sv = st4[k];               // wave-uniform broadcast b128
            m0 = fmaxf(m0, sv.x + tc[4 * k + 0]);
            m1 = fmaxf(m1, sv.y + tc[4 * k + 1]);
            m2 = fmaxf(m2, sv.z + tc[4 * k + 2]);
            m3 = fmaxf(m3, sv.w + tc[4 * k + 3]);
        }
        sm.pv[tid] = fmaxf(fmaxf(m0, m1), fmaxf(m2, m3));
        lds_barrier();
        if (tid < TT) {
            float bv = fmaxf(fmaxf(sm.pv[j], sm.pv[j + 128]),
                             fmaxf(sm.pv[j + 256], sm.pv[j + 384]));
            wsb[t * TT + j] = bv;             // m_t row (pre-emission max)
            sm.state[j] = bv + xv;
            xv = xn;
        }
        lds_barrier();
    }

    // Drain our m-history stores and make them visible block-wide.
    __syncthreads();

    // ---- last_tag: exact first-index argmax over state (wave 0) ----
    int c = 0; float mv = 0.0f;
    const int l = tid;                        // lane id when tid < 64
    if (tid < 64) {
        float s0 = sm.state[l], s1 = sm.state[l + 64];
        float mm = fmaxf(s0, s1);
        #pragma unroll
        for (int off = 1; off < 64; off <<= 1)
            mm = fmaxf(mm, __shfl_xor(mm, off));
        ull blo = __ballot(s0 == mm);         // lo half: indices 0..63 (first)
        if (blo) c = __ffsll(blo) - 1;
        else     c = 64 + __ffsll(__ballot(s1 == mm)) - 1;
        if (lenb > 1) mv = wsb[(lenb - 1) * TT + c];   // m_{len-1}[c]
    }

    // ---- chunked backward walk (wave 0 walks; all threads stage) ----
    // Semantics (matches reference): tags[t] = c, THEN c = bp_t[c].
    int rhi = lenb - 2;                       // highest source row needed
    while (rhi >= 0) {
        int r0 = rhi - (CH - 1); if (r0 < 0) r0 = 0;
        int nrows = rhi - r0 + 1;
        const float4* wm4 = reinterpret_cast<const float4*>(wsb + r0 * TT);
        const float4* wx4 = reinterpret_cast<const float4*>(xb  + r0 * TT);
        float4* bm4 = reinterpret_cast<float4*>(bm);
        float4* bx4 = reinterpret_cast<float4*>(bx);
        int n4 = nrows * (TT / 4);
        for (int i4 = tid; i4 < n4; i4 += NTH) {
            bm4[i4] = wm4[i4];
            float4 v = wx4[i4];
            // row 0 holds state_0 directly: no emission re-add
            if (r0 == 0 && i4 < TT / 4) { v.x = 0.f; v.y = 0.f; v.z = 0.f; v.w = 0.f; }
            bx4[i4] = v;
        }
        lds_barrier();
        if (tid < 64) {
            for (int tt = r0 + nrows; tt >= r0 + 1; --tt) {
                int row = (tt - 1 - r0) * TT;
                // bit-exact recompute of forward scores:
                // state_{t-1}[i] = m + x (same operands/order as forward)
                float slo = (bm[row + l]      + bx[row + l])      + tT[c * TTP + l];
                float shi = (bm[row + 64 + l] + bx[row + 64 + l]) + tT[c * TTP + 64 + l];
                ull blo = __ballot(slo == mv);
                int nc;
                if (blo) nc = __ffsll(blo) - 1;              // first i in 0..63
                else     nc = 64 + __ffsll(__ballot(shi == mv)) - 1;
                if (l == 0) sm.tags[tt] = (unsigned char)c;  // CURRENT tag at tt
                c = nc;                                      // tag at tt-1
                mv = bm[row + c];             // m_{tt-1}[c] for next step
            }
        }
        lds_barrier();                        // protect bm/bx before reload
        rhi = r0 - 1;
    }
    if (tid == 0) sm.tags[0] = (unsigned char)c;
    lds_barrier();

    int* outb = out + (size_t)b * LL;
    for (int tt = tid; tt < LL; tt += NTH)
        outb[tt] = (tt < lenb) ? (int)sm.tags[tt] : 0;
}

// ===================== fallback (no workspace): round-0 kernel =====================
struct SmallSmem {
    float state[TT];
    float pv[NTH];
    int   pi[NTH];
    unsigned char tags[LL];
};

__global__ __launch_bounds__(NTH)
void viterbi_kernel(const float* __restrict__ x,
                    const int* __restrict__ lengths,
                    const float* __restrict__ trans,
                    int* __restrict__ out) {
    __shared__ SmallSmem sm;
    extern __shared__ unsigned char bp[];   // LL*TT bytes

    const int b   = blockIdx.x;
    const int tid = threadIdx.x;
    const int j   = tid & (TT - 1);
    const int q   = tid >> 7;

    int lenb = lengths[b];
    if (lenb < 1) lenb = 1;
    if (lenb > LL) lenb = LL;

    float tc[32];
    #pragma unroll
    for (int ii = 0; ii < 32; ++ii)
        tc[ii] = trans[(q * 32 + ii) * TT + j];
    #pragma unroll
    for (int ii = 0; ii < 32; ++ii)
        asm volatile("" : "+v"(tc[ii]));

    const float* xb = x + (size_t)b * LL * TT;
    if (tid < TT) sm.state[tid] = xb[tid];

    float xv_cur = 0.0f, xv_next = 0.0f;
    if (tid < TT && lenb > 1) xv_cur = xb[TT + j];
    lds_barrier();

    for (int t = 1; t < lenb; ++t) {
        if (tid < TT) {
            int tn = (t + 1 < lenb) ? (t + 1) : (lenb - 1);
            xv_next = xb[tn * TT + j];
        }
        float best0 = -3.4e38f, best1 = -3.4e38f, best2 = -3.4e38f, best3 = -3.4e38f;
        int   bi0 = 0, bi1 = 1, bi2 = 2, bi3 = 3;
        const float4* st4 = reinterpret_cast<const float4*>(sm.state + q * 32);
        #pragma unroll
        for (int k = 0; k < 8; ++k) {
            float4 sv = st4[k];
            float s0 = sv.x + tc[4 * k + 0];
            float s1 = sv.y + tc[4 * k + 1];
            float s2 = sv.z + tc[4 * k + 2];
            float s3 = sv.w + tc[4 * k + 3];
            if (s0 > best0) { best0 = s0; bi0 = 4 * k + 0; }
            if (s1 > best1) { best1 = s1; bi1 = 4 * k + 1; }
            if (s2 > best2) { best2 = s2; bi2 = 4 * k + 2; }
            if (s3 > best3) { best3 = s3; bi3 = 4 * k + 3; }
        }
        float bb = best0; int bi = bi0;
        if (best1 > bb || (best1 == bb && bi1 < bi)) { bb = best1; bi = bi1; }
        if (best2 > bb || (best2 == bb && bi2 < bi)) { bb = best2; bi = bi2; }
        if (best3 > bb || (best3 == bb && bi3 < bi)) { bb = best3; bi = bi3; }
        sm.pv[tid] = bb;
        sm.pi[tid] = bi + q * 32;
        lds_barrier();

        if (tid < TT) {
            float bv = sm.pv[j];       int ix = sm.pi[j];
            float v1 = sm.pv[j + 128]; int i1 = sm.pi[j + 128];
            float v2 = sm.pv[j + 256]; int i2 = sm.pi[j + 256];
            float v3 = sm.pv[j + 384]; int i3 = sm.pi[j + 384];
            if (v1 > bv) { bv = v1; ix = i1; }
            if (v2 > bv) { bv = v2; ix = i2; }
            if (v3 > bv) { bv = v3; ix = i3; }
            sm.state[j] = bv + xv_cur;
            bp[t * TT + j] = (unsigned char)ix;
            xv_cur = xv_next;
        }
        lds_barrier();
    }

    if (tid == 0) {
        float bv = sm.state[0]; int ix = 0;
        for (int i = 1; i < TT; ++i) {
            float v = sm.state[i];
            if (v > bv) { bv = v; ix = i; }
        }
        int carry = ix;
        for (int t = lenb - 1; t >= 1; --t) {
            sm.tags[t] = (unsigned char)carry;
            carry = bp[t * TT + carry];
        }
        sm.tags[0] = (unsigned char)carry;
    }
    lds_barrier();

    int* outb = out + (size_t)b * LL;
    for (int t = tid; t < LL; t += NTH)
        outb[t] = (t < lenb) ? (int)sm.tags[t] : 0;
}

extern "C" void kernel_launch(void* const* d_in, const int* in_sizes, int n_in,
                              void* d_out, int out_size, void* d_ws, size_t ws_size,
                              hipStream_t stream) {
    const float* x       = (const float*)d_in[0];
    const int*   lengths = (const int*)d_in[1];
    // d_in[2] = tags (unused by decode)
    const float* trans   = (const float*)d_in[3];
    int*         out     = (int*)d_out;

    const size_t ws_needed = (size_t)BB * LL * TT * sizeof(float);  // 134 MB

    if (d_ws != nullptr && ws_size >= ws_needed) {
        // tT (padded, 64.5 KB) + bm/bx staging (64 KB) dynamic; ~3.6 KB static
        const int dyn = (TTP * TT + 2 * CH * TT) * (int)sizeof(float);  // 131584
        hipFuncSetAttribute((const void*)&viterbi_ws_kernel,
                            hipFuncAttributeMaxDynamicSharedMemorySize, dyn);
        viterbi_ws_kernel<<<BB, NTH, dyn, stream>>>(x, lengths, trans, out,
                                                    (float*)d_ws);
    } else {
        const int dyn = LL * TT;  // 131072 bytes of backpointers
        hipFuncSetAttribute((const void*)&viterbi_kernel,
                            hipFuncAttributeMaxDynamicSharedMemorySize, dyn);
        viterbi_kernel<<<BB, NTH, dyn, stream>>>(x, lengths, trans, out);
    }
}